// Round 10
// baseline (88.338 us; speedup 1.0000x reference)
//
#include <hip/hip_runtime.h>
#include <math.h>

#define NPTS 4096
#define NB 4
#define EPSF 1e-6f

// ============================================================================
// gravity_align + t_center (exact reference arithmetic; bit-exact R1-R9).
// ============================================================================
__device__ __forceinline__ void gravity_align_rt(
    const float* __restrict__ g_p, const float* __restrict__ g_q,
    const float* sums, int b, float* R_out, float* t_out) {
    float gpx = g_p[3 * b + 0], gpy = g_p[3 * b + 1], gpz = g_p[3 * b + 2];
    float gqx = g_q[3 * b + 0], gqy = g_q[3 * b + 1], gqz = g_q[3 * b + 2];
    float nu = sqrtf(gpx * gpx + gpy * gpy + gpz * gpz);
    float du = fmaxf(nu, EPSF);
    float ux = gpx / du, uy = gpy / du, uz = gpz / du;
    float nv = sqrtf(gqx * gqx + gqy * gqy + gqz * gqz);
    float dv = fmaxf(nv, EPSF);
    float vx = gqx / dv, vy = gqy / dv, vz = gqz / dv;

    float ax = uy * vz - uz * vy;
    float ay = uz * vx - ux * vz;
    float az = ux * vy - uy * vx;
    float an = sqrtf(ax * ax + ay * ay + az * az);
    float dot = ux * vx + uy * vy + uz * vz;
    dot = fminf(1.0f, fmaxf(-1.0f, dot));
    bool parallel = (an < 1e-6f);

    float kx = ax / (an + EPSF), ky = ay / (an + EPSF), kz = az / (an + EPSF);
    float theta = acosf(dot);
    float st = sinf(theta), ct = cosf(theta);

    float K[9] = {0.f, -kz, ky,  kz, 0.f, -kx,  -ky, kx, 0.f};
    float KK[9];
    for (int i = 0; i < 3; ++i)
        for (int j = 0; j < 3; ++j) {
            float s2 = 0.f;
            for (int l = 0; l < 3; ++l) s2 += K[i * 3 + l] * K[l * 3 + j];
            KK[i * 3 + j] = s2;
        }
    float R[9];
    for (int i = 0; i < 9; ++i) {
        float I = (i == 0 || i == 4 || i == 8) ? 1.f : 0.f;
        R[i] = I + st * K[i] + (1.f - ct) * KK[i];
    }
    if (parallel) {
        if (dot < 0.f) {
            float bx, by, bz;
            if (fabsf(ux) < 0.9f) { bx = 1.f; by = 0.f; bz = 0.f; }
            else                  { bx = 0.f; by = 1.f; bz = 0.f; }
            float cx = uy * bz - uz * by;
            float cy = uz * bx - ux * bz;
            float cz = ux * by - uy * bx;
            float cn = sqrtf(cx * cx + cy * cy + cz * cz);
            float cd = fmaxf(cn, EPSF);
            cx /= cd; cy /= cd; cz /= cd;
            float K2[9] = {0.f, -cz, cy,  cz, 0.f, -cx,  -cy, cx, 0.f};
            float K2K2[9];
            for (int i = 0; i < 3; ++i)
                for (int j = 0; j < 3; ++j) {
                    float s2 = 0.f;
                    for (int l = 0; l < 3; ++l) s2 += K2[i * 3 + l] * K2[l * 3 + j];
                    K2K2[i * 3 + j] = s2;
                }
            for (int i = 0; i < 9; ++i) {
                float I = (i == 0 || i == 4 || i == 8) ? 1.f : 0.f;
                R[i] = I + 2.f * K2K2[i];
            }
        } else if (dot > 0.f) {
            for (int i = 0; i < 9; ++i) R[i] = (i == 0 || i == 4 || i == 8) ? 1.f : 0.f;
        }
    }
    float ms0 = sums[0] / (float)NPTS, ms1 = sums[1] / (float)NPTS, ms2 = sums[2] / (float)NPTS;
    float mt0 = sums[3] / (float)NPTS, mt1 = sums[4] / (float)NPTS, mt2 = sums[5] / (float)NPTS;
    for (int i = 0; i < 9; ++i) R_out[i] = R[i];
    t_out[0] = mt0 - (R[0] * ms0 + R[1] * ms1 + R[2] * ms2);
    t_out[1] = mt1 - (R[3] * ms0 + R[4] * ms1 + R[5] * ms2);
    t_out[2] = mt2 - (R[6] * ms0 + R[7] * ms1 + R[8] * ms2);
}

// ============================================================================
// mega2: single persistent kernel, 512 blocks x 1024 thr (R7-proven fully
// co-resident: 2 blocks/CU, 64KB LDS, 97% occupancy). ONE hand-rolled
// device-scope barrier instead of kernel boundaries (cg grid.sync = 160us
// on this chip, R7; launch gap ~10us each, R9).
//   M : every block computes ITS batch's means (bit-exact 256-thr pattern,
//       sync-reduced; 9 syncs) + R/t -> registers. No k0, no pack arrays.
//   A : stage other-set in LDS from RAW inputs (same exprs as k0 -> same
//       bits); verbatim R5 scan; write nn/idx.
//   BAR: memset-0 counter; atomicAdd; target (old&~511)+512; acquire spin
//       with s_sleep; bailout so a bug fails visibly, never hangs.
//   B : blocks with x==0 (8 of them): R9-proven 4-pass radix median +
//       weights, snr/tn recomputed from raw + R (identical expr order).
// Static LDS EXACTLY 64KB (R6 lesson): all scratch aliased into stage4.
// ============================================================================
__global__ __launch_bounds__(1024, 8) void mega2(
    const float* __restrict__ src, const float* __restrict__ tgt,
    const float* __restrict__ src_n, const float* __restrict__ tgt_n,
    const float* __restrict__ g_p, const float* __restrict__ g_q,
    const float* __restrict__ k_p, const float* __restrict__ k_q,
    float* __restrict__ nnp, int* __restrict__ idxp,
    float* __restrict__ nnq, int* __restrict__ idxq,
    unsigned int* __restrict__ bar, float* __restrict__ out)
{
    const int tid = threadIdx.x;
    const int bid = blockIdx.x;
    const int x = bid & 63;
    const int b = (bid >> 6) & 3;
    const int z = bid >> 8;

    __shared__ float4 stage4[NPTS];   // 64 KB, aliased by every phase
    float* sf = (float*)stage4;
    int* si = (int*)stage4;

    const float* S  = src   + (size_t)b * 3 * NPTS;
    const float* T  = tgt   + (size_t)b * 3 * NPTS;
    const float* SN = src_n + (size_t)b * 3 * NPTS;
    const float* TN = tgt_n + (size_t)b * 3 * NPTS;

    // ===== M: means (bit-exact 256-thr accumulation + per-channel tree) ====
    {
        float acc[6] = {0.f, 0.f, 0.f, 0.f, 0.f, 0.f};
        if (tid < 256) {
            for (int n = tid; n < NPTS; n += 256) {
                acc[0] += S[n]; acc[1] += S[NPTS + n]; acc[2] += S[2 * NPTS + n];
                acc[3] += T[n]; acc[4] += T[NPTS + n]; acc[5] += T[2 * NPTS + n];
            }
        }
        // red6[c][tid] = sf[c*256+tid]; tree pairings identical per channel
        if (tid < 256) {
            #pragma unroll
            for (int c = 0; c < 6; ++c) sf[c * 256 + tid] = acc[c];
        }
        __syncthreads();
        for (int s = 128; s > 0; s >>= 1) {
            if (tid < s) {
                #pragma unroll
                for (int c = 0; c < 6; ++c) sf[c * 256 + tid] += sf[c * 256 + tid + s];
            }
            __syncthreads();
        }
        if (tid == 0) {
            float sums[6];
            #pragma unroll
            for (int c = 0; c < 6; ++c) sums[c] = sf[c * 256];
            gravity_align_rt(g_p, g_q, sums, b, sf + 1536, sf + 1545);
        }
        __syncthreads();
    }
    const float R0 = sf[1536], R1 = sf[1537], R2 = sf[1538];
    const float R3 = sf[1539], R4 = sf[1540], R5 = sf[1541];
    const float R6 = sf[1542], R7 = sf[1543], R8 = sf[1544];
    const float t0 = sf[1545], t1 = sf[1546], t2 = sf[1547];
    __syncthreads();   // everyone has R/t in regs before staging overwrites

    // ===== A: stage + own-points + scan (values bit-identical to R5/R9) ====
    const int nl = tid & 63;
    const int stripe = tid >> 6;
    const int n = x * 64 + nl;
    float4 p;
    {
        if (z == 0) {
            // stage = q-points from raw tgt
            for (int i = tid; i < NPTS; i += 1024) {
                float q0 = T[i], q1 = T[NPTS + i], q2 = T[2 * NPTS + i];
                float w = (q0 * q0 + q1 * q1 + q2 * q2) * -0.5f;
                stage4[i] = make_float4(q0, q1, q2, w);
            }
            // own = p-point (R-transformed)
            float s0 = S[n], s1 = S[NPTS + n], s2 = S[2 * NPTS + n];
            float p0 = R0 * s0 + R1 * s1 + R2 * s2 + t0;
            float p1 = R3 * s0 + R4 * s1 + R5 * s2 + t1;
            float p2 = R6 * s0 + R7 * s1 + R8 * s2 + t2;
            p = make_float4(p0, p1, p2, p0 * p0 + p1 * p1 + p2 * p2);
        } else {
            // stage = p-points (R-transformed src)
            for (int i = tid; i < NPTS; i += 1024) {
                float s0 = S[i], s1 = S[NPTS + i], s2 = S[2 * NPTS + i];
                float p0 = R0 * s0 + R1 * s1 + R2 * s2 + t0;
                float p1 = R3 * s0 + R4 * s1 + R5 * s2 + t1;
                float p2 = R6 * s0 + R7 * s1 + R8 * s2 + t2;
                float w = (p0 * p0 + p1 * p1 + p2 * p2) * -0.5f;
                stage4[i] = make_float4(p0, p1, p2, w);
            }
            // own = q-point (raw tgt)
            float q0 = T[n], q1 = T[NPTS + n], q2 = T[2 * NPTS + n];
            p = make_float4(q0, q1, q2, q0 * q0 + q1 * q1 + q2 * q2);
        }
        __syncthreads();

        const int m0 = stripe << 8;
        float best = -3.4e38f;
        int bi = m0;
        #pragma unroll 8
        for (int m = m0; m < m0 + 256; ++m) {
            float4 q = stage4[m];
            float s = fmaf(p.x, q.x, fmaf(p.y, q.y, fmaf(p.z, q.z, q.w)));
            if (s > best) { best = s; bi = m; }
        }
        __syncthreads();

        float* combd = sf;
        int* combi = (int*)(combd + 1024);
        combd[tid] = best;
        combi[tid] = bi;
        __syncthreads();
        if (stripe == 0) {
            for (int s2 = 1; s2 < 16; ++s2) {
                float d2 = combd[s2 * 64 + nl];
                int i2 = combi[s2 * 64 + nl];
                if (d2 > best) { best = d2; bi = i2; }  // ties: lower m wins
            }
            float d = fmaf(-2.0f, best, p.w);
            float* nn = z ? nnq : nnp;
            int* idx = z ? idxq : idxp;
            nn[b * NPTS + n] = sqrtf(fmaxf(d, 0.f) + EPSF);
            idx[b * NPTS + n] = bi;
        }
    }

    // ===== BAR: hand-rolled device barrier ================================
    __syncthreads();
    if (tid == 0) {
        __threadfence();                       // release nn/idx device-wide
        unsigned int old = atomicAdd(bar, 1u);
        unsigned int target = (old & ~511u) + 512u;
        int guard = 0;
        while (__hip_atomic_load(bar, __ATOMIC_ACQUIRE, __HIP_MEMORY_SCOPE_AGENT) < target) {
            __builtin_amdgcn_s_sleep(2);
            if (++guard > (1 << 22)) break;    // fail visibly, never hang
        }
        __threadfence();
    }
    __syncthreads();

    if (x != 0) return;

    // ===== B: median (R9 radix, proven) + weights for (b, z) ==============
    const float* a = (z ? nnq : nnp) + b * NPTS;
    unsigned int v[4];
    float vf[4];
    #pragma unroll
    for (int j = 0; j < 4; ++j) {
        float xx = a[tid + j * 1024];
        vf[j] = xx;
        v[j] = __float_as_uint(xx);   // positive floats: uint order == float order
    }

    int* hist = si;             // [16][256] = 4096 ints
    int* tot = si + 4096;       // 256
    int* digit_s = si + 4352;
    int* base_s = si + 4353;

    const int wid = tid >> 6;
    const int lane = tid & 63;
    const int shifts[4]   = {23, 15, 7, 0};
    const unsigned him[4] = {0x00000000u, 0x7F800000u, 0x7FFF8000u, 0x7FFFFF80u};
    const unsigned dm[4]  = {0xFFu, 0xFFu, 0xFFu, 0x7Fu};

    unsigned int prefix = 0u;
    int rank = 2047;

    __syncthreads();   // stage reuse as hist
    for (int pss = 0; pss < 4; ++pss) {
        const int sh = shifts[pss];
        const unsigned himask = him[pss];
        const unsigned dmask = dm[pss];

        for (int k2 = lane; k2 < 256; k2 += 64) hist[wid * 256 + k2] = 0;
        __syncthreads();

        #pragma unroll
        for (int j = 0; j < 4; ++j) {
            if ((v[j] & himask) == prefix)
                atomicAdd(&hist[wid * 256 + ((v[j] >> sh) & dmask)], 1);
        }
        __syncthreads();

        if (tid < 256) {
            int t = 0;
            #pragma unroll
            for (int w = 0; w < 16; ++w) t += hist[w * 256 + tid];
            tot[tid] = t;
        }
        __syncthreads();

        if (wid == 0) {
            int c0 = tot[4 * lane + 0], c1 = tot[4 * lane + 1];
            int c2 = tot[4 * lane + 2], c3 = tot[4 * lane + 3];
            int s = c0 + c1 + c2 + c3;
            int incl = s;
            #pragma unroll
            for (int o = 1; o < 64; o <<= 1) {
                int t = __shfl_up(incl, o, 64);
                if (lane >= o) incl += t;
            }
            int base = incl - s;
            int cs[4] = {c0, c1, c2, c3};
            #pragma unroll
            for (int k2 = 0; k2 < 4; ++k2) {
                if (cs[k2] > 0 && rank >= base && rank < base + cs[k2]) {
                    *digit_s = 4 * lane + k2;   // unique writer
                    *base_s = base;
                }
                base += cs[k2];
            }
        }
        __syncthreads();
        prefix |= ((unsigned)(*digit_s)) << sh;
        rank -= *base_s;
        __syncthreads();
    }
    const float tauv = 3.0f * __uint_as_float(prefix);

    const float gx = g_q[3 * b + 0], gy = g_q[3 * b + 1], gz = g_q[3 * b + 2];
    const float kp = k_p[b], kq = k_q[b];
    const float keff = kp * kq / (kp + kq + EPSF);

    #pragma unroll
    for (int j = 0; j < 4; ++j) {
        const int nn2 = tid + j * 1024;
        float w;
        if (z == 0) {
            float a0 = SN[nn2], a1 = SN[NPTS + nn2], a2 = SN[2 * NPTS + nn2];
            float snx = R0 * a0 + R1 * a1 + R2 * a2;
            float sny = R3 * a0 + R4 * a1 + R5 * a2;
            float snz = R6 * a0 + R7 * a1 + R8 * a2;
            float inc = snx * gx + sny * gy + snz * gz;
            int jj = idxp[b * NPTS + nn2];
            float tnx = TN[jj], tny = TN[NPTS + jj], tnz = TN[2 * NPTS + jj];
            float incr = tnx * gx + tny * gy + tnz * gz;
            float diff = inc - incr;
            float arg = 9.0f - keff * diff * diff;
            float sig = 1.f / (1.f + expf(-arg));
            float geom = (vf[j] <= tauv) ? 1.f : 0.f;
            w = sig * geom;
        } else {
            float tnx = TN[nn2], tny = TN[NPTS + nn2], tnz = TN[2 * NPTS + nn2];
            float inc = tnx * gx + tny * gy + tnz * gz;
            int jj = idxq[b * NPTS + nn2];
            float a0 = SN[jj], a1 = SN[NPTS + jj], a2 = SN[2 * NPTS + jj];
            float snx = R0 * a0 + R1 * a1 + R2 * a2;
            float sny = R3 * a0 + R4 * a1 + R5 * a2;
            float snz = R6 * a0 + R7 * a1 + R8 * a2;
            float incr = snx * gx + sny * gy + snz * gz;
            float diff = inc - incr;
            float arg = 9.0f - keff * diff * diff;
            float sig = 1.f / (1.f + expf(-arg));
            float geom = (vf[j] <= tauv) ? 1.f : 0.f;
            w = sig * geom;
        }
        out[z * (NB * NPTS) + b * NPTS + nn2] = w;
    }
}

// ============================================================================
// Fallback: verbatim R9 3-kernel pipeline (53.3us, absmax 0.0), used only
// if the barrier-reset memset errors (e.g. graph-capture refusal).
// ============================================================================
__global__ void k0_setup(const float* __restrict__ src, const float* __restrict__ tgt,
                         const float* __restrict__ src_n, const float* __restrict__ tgt_n,
                         const float* __restrict__ g_p, const float* __restrict__ g_q,
                         float4* __restrict__ p4, float4* __restrict__ q4,
                         float4* __restrict__ snr4, float4* __restrict__ tn4) {
    const int b = blockIdx.x;
    const int tid = threadIdx.x;
    const float* S  = src   + (size_t)b * 3 * NPTS;
    const float* T  = tgt   + (size_t)b * 3 * NPTS;
    const float* SN = src_n + (size_t)b * 3 * NPTS;
    const float* TN = tgt_n + (size_t)b * 3 * NPTS;

    __shared__ float red[256];
    __shared__ float sums[6];
    __shared__ float Rg[9], tc[3];

    float acc[6] = {0.f, 0.f, 0.f, 0.f, 0.f, 0.f};
    if (tid < 256) {
        for (int n = tid; n < NPTS; n += 256) {
            acc[0] += S[n]; acc[1] += S[NPTS + n]; acc[2] += S[2 * NPTS + n];
            acc[3] += T[n]; acc[4] += T[NPTS + n]; acc[5] += T[2 * NPTS + n];
        }
    }
    for (int c = 0; c < 6; ++c) {
        if (tid < 256) red[tid] = acc[c];
        __syncthreads();
        for (int s = 128; s > 0; s >>= 1) {
            if (tid < s) red[tid] += red[tid + s];
            __syncthreads();
        }
        if (tid == 0) sums[c] = red[0];
        __syncthreads();
    }

    if (tid == 0) gravity_align_rt(g_p, g_q, sums, b, Rg, tc);
    __syncthreads();

    const float R0 = Rg[0], R1 = Rg[1], R2 = Rg[2];
    const float R3 = Rg[3], R4 = Rg[4], R5 = Rg[5];
    const float R6 = Rg[6], R7 = Rg[7], R8 = Rg[8];
    const float t0 = tc[0], t1 = tc[1], t2 = tc[2];

    for (int n = tid; n < NPTS; n += 1024) {
        float s0 = S[n], s1 = S[NPTS + n], s2 = S[2 * NPTS + n];
        float p0 = R0 * s0 + R1 * s1 + R2 * s2 + t0;
        float p1 = R3 * s0 + R4 * s1 + R5 * s2 + t1;
        float p2 = R6 * s0 + R7 * s1 + R8 * s2 + t2;
        p4[b * NPTS + n] = make_float4(p0, p1, p2, p0 * p0 + p1 * p1 + p2 * p2);

        float q0 = T[n], q1 = T[NPTS + n], q2 = T[2 * NPTS + n];
        q4[b * NPTS + n] = make_float4(q0, q1, q2, q0 * q0 + q1 * q1 + q2 * q2);

        float a0 = SN[n], a1 = SN[NPTS + n], a2 = SN[2 * NPTS + n];
        snr4[b * NPTS + n] = make_float4(R0 * a0 + R1 * a1 + R2 * a2,
                                         R3 * a0 + R4 * a1 + R5 * a2,
                                         R6 * a0 + R7 * a1 + R8 * a2, 0.f);
        float c0 = TN[n], c1 = TN[NPTS + n], c2 = TN[2 * NPTS + n];
        tn4[b * NPTS + n] = make_float4(c0, c1, c2, 0.f);
    }
}

__global__ void k1_nn(const float4* __restrict__ p4, const float4* __restrict__ q4,
                      float* __restrict__ nnp, int* __restrict__ idxp,
                      float* __restrict__ nnq, int* __restrict__ idxq) {
    const int b = blockIdx.y;
    const int z = blockIdx.z;
    const float4* own = z ? q4 : p4;
    const float4* oth = z ? p4 : q4;
    float* nn = z ? nnq : nnp;
    int* idx = z ? idxq : idxp;

    __shared__ float4 stage[NPTS];
    const int tid = threadIdx.x;
    for (int i = tid; i < NPTS; i += 1024) {
        float4 v = oth[b * NPTS + i];
        v.w *= -0.5f;
        stage[i] = v;
    }

    const int nl = tid & 63;
    const int stripe = tid >> 6;
    const int n = blockIdx.x * 64 + nl;
    const float4 p = own[b * NPTS + n];
    __syncthreads();

    const int m0 = stripe << 8;
    float best = -3.4e38f;
    int bi = m0;
    #pragma unroll 8
    for (int m = m0; m < m0 + 256; ++m) {
        float4 q = stage[m];
        float s = fmaf(p.x, q.x, fmaf(p.y, q.y, fmaf(p.z, q.z, q.w)));
        if (s > best) { best = s; bi = m; }
    }
    __syncthreads();

    float* combd = (float*)stage;
    int* combi = (int*)(combd + 1024);
    combd[tid] = best;
    combi[tid] = bi;
    __syncthreads();
    if (stripe == 0) {
        for (int s2 = 1; s2 < 16; ++s2) {
            float d2 = combd[s2 * 64 + nl];
            int i2 = combi[s2 * 64 + nl];
            if (d2 > best) { best = d2; bi = i2; }
        }
        float d = fmaf(-2.0f, best, p.w);
        nn[b * NPTS + n] = sqrtf(fmaxf(d, 0.f) + EPSF);
        idx[b * NPTS + n] = bi;
    }
}

__global__ void kc_tau_w(const float* __restrict__ nnp, const float* __restrict__ nnq,
                         const float4* __restrict__ snr4, const float4* __restrict__ tn4,
                         const int* __restrict__ idxp, const int* __restrict__ idxq,
                         const float* __restrict__ g_q, const float* __restrict__ k_p,
                         const float* __restrict__ k_q, float* __restrict__ out) {
    const int b = blockIdx.x;
    const int z = blockIdx.y;
    const int tid = threadIdx.x;
    const int wid = tid >> 6;
    const int lane = tid & 63;
    const float* a = (z ? nnq : nnp) + b * NPTS;

    unsigned int v[4];
    float vf[4];
    #pragma unroll
    for (int j = 0; j < 4; ++j) {
        float x = a[tid + j * 1024];
        vf[j] = x;
        v[j] = __float_as_uint(x);
    }

    __shared__ int hist[16][256];
    __shared__ int tot[256];
    __shared__ int digit_s, base_s;

    const int shifts[4]   = {23, 15, 7, 0};
    const unsigned him[4] = {0x00000000u, 0x7F800000u, 0x7FFF8000u, 0x7FFFFF80u};
    const unsigned dm[4]  = {0xFFu, 0xFFu, 0xFFu, 0x7Fu};

    unsigned int prefix = 0u;
    int rank = 2047;

    for (int p = 0; p < 4; ++p) {
        const int sh = shifts[p];
        const unsigned himask = him[p];
        const unsigned dmask = dm[p];

        for (int k2 = lane; k2 < 256; k2 += 64) hist[wid][k2] = 0;
        __syncthreads();

        #pragma unroll
        for (int j = 0; j < 4; ++j) {
            if ((v[j] & himask) == prefix)
                atomicAdd(&hist[wid][(v[j] >> sh) & dmask], 1);
        }
        __syncthreads();

        if (tid < 256) {
            int t = 0;
            #pragma unroll
            for (int w = 0; w < 16; ++w) t += hist[w][tid];
            tot[tid] = t;
        }
        __syncthreads();

        if (wid == 0) {
            int c0 = tot[4 * lane + 0], c1 = tot[4 * lane + 1];
            int c2 = tot[4 * lane + 2], c3 = tot[4 * lane + 3];
            int s = c0 + c1 + c2 + c3;
            int incl = s;
            #pragma unroll
            for (int o = 1; o < 64; o <<= 1) {
                int t = __shfl_up(incl, o, 64);
                if (lane >= o) incl += t;
            }
            int base = incl - s;
            int cs[4] = {c0, c1, c2, c3};
            #pragma unroll
            for (int k2 = 0; k2 < 4; ++k2) {
                if (cs[k2] > 0 && rank >= base && rank < base + cs[k2]) {
                    digit_s = 4 * lane + k2;
                    base_s = base;
                }
                base += cs[k2];
            }
        }
        __syncthreads();
        prefix |= ((unsigned)digit_s) << sh;
        rank -= base_s;
        __syncthreads();
    }
    const float tauv = 3.0f * __uint_as_float(prefix);

    const float gx = g_q[3 * b + 0], gy = g_q[3 * b + 1], gz = g_q[3 * b + 2];
    const float kp = k_p[b], kq = k_q[b];
    const float keff = kp * kq / (kp + kq + EPSF);

    #pragma unroll
    for (int j = 0; j < 4; ++j) {
        const int n = tid + j * 1024;
        float w;
        if (z == 0) {
            float4 sn = snr4[b * NPTS + n];
            float inc = sn.x * gx + sn.y * gy + sn.z * gz;
            int jj = idxp[b * NPTS + n];
            float4 tn = tn4[b * NPTS + jj];
            float incr = tn.x * gx + tn.y * gy + tn.z * gz;
            float diff = inc - incr;
            float arg = 9.0f - keff * diff * diff;
            float sig = 1.f / (1.f + expf(-arg));
            float geom = (vf[j] <= tauv) ? 1.f : 0.f;
            w = sig * geom;
        } else {
            float4 tn = tn4[b * NPTS + n];
            float inc = tn.x * gx + tn.y * gy + tn.z * gz;
            int jj = idxq[b * NPTS + n];
            float4 sn = snr4[b * NPTS + jj];
            float incr = sn.x * gx + sn.y * gy + sn.z * gz;
            float diff = inc - incr;
            float arg = 9.0f - keff * diff * diff;
            float sig = 1.f / (1.f + expf(-arg));
            float geom = (vf[j] <= tauv) ? 1.f : 0.f;
            w = sig * geom;
        }
        out[z * (NB * NPTS) + b * NPTS + n] = w;
    }
}

extern "C" void kernel_launch(void* const* d_in, const int* in_sizes, int n_in,
                              void* d_out, int out_size, void* d_ws, size_t ws_size,
                              hipStream_t stream) {
    const float* src   = (const float*)d_in[0];
    const float* tgt   = (const float*)d_in[1];
    const float* src_n = (const float*)d_in[2];
    const float* tgt_n = (const float*)d_in[3];
    const float* g_p   = (const float*)d_in[4];
    const float* k_p   = (const float*)d_in[5];
    const float* g_q   = (const float*)d_in[6];
    const float* k_q   = (const float*)d_in[7];
    float* out = (float*)d_out;

    const int BN = NB * NPTS;
    float4* p4   = (float4*)d_ws;      // fallback-only
    float4* q4   = p4 + BN;
    float4* snr4 = q4 + BN;
    float4* tn4  = snr4 + BN;
    float* nnp = (float*)(tn4 + BN);
    float* nnq = nnp + BN;
    int* idxp = (int*)(nnq + BN);
    int* idxq = idxp + BN;
    unsigned int* bar = (unsigned int*)(idxq + BN);   // 64B barrier slot

    hipError_t err = hipMemsetAsync(bar, 0, 64, stream);
    if (err == hipSuccess) {
        mega2<<<dim3(512), dim3(1024), 0, stream>>>(
            src, tgt, src_n, tgt_n, g_p, g_q, k_p, k_q,
            nnp, idxp, nnq, idxq, bar, out);
    } else {
        // Proven R9 path (53.3 us, absmax 0.0).
        k0_setup<<<dim3(NB), dim3(1024), 0, stream>>>(src, tgt, src_n, tgt_n, g_p, g_q,
                                                      p4, q4, snr4, tn4);
        k1_nn<<<dim3(NPTS / 64, NB, 2), dim3(1024), 0, stream>>>(p4, q4, nnp, idxp, nnq, idxq);
        kc_tau_w<<<dim3(NB, 2), dim3(1024), 0, stream>>>(nnp, nnq, snr4, tn4, idxp, idxq,
                                                         g_q, k_p, k_q, out);
    }
}

// Round 11
// 46.554 us; speedup vs baseline: 1.8975x; 1.8975x over previous
//
#include <hip/hip_runtime.h>
#include <math.h>

#define NPTS 4096
#define NB 4
#define EPSF 1e-6f

// ============================================================================
// gravity_align + t_center (exact reference arithmetic; bit-exact R1-R10).
// ============================================================================
__device__ __forceinline__ void gravity_align_rt(
    const float* __restrict__ g_p, const float* __restrict__ g_q,
    const float* sums, int b, float* R_out, float* t_out) {
    float gpx = g_p[3 * b + 0], gpy = g_p[3 * b + 1], gpz = g_p[3 * b + 2];
    float gqx = g_q[3 * b + 0], gqy = g_q[3 * b + 1], gqz = g_q[3 * b + 2];
    float nu = sqrtf(gpx * gpx + gpy * gpy + gpz * gpz);
    float du = fmaxf(nu, EPSF);
    float ux = gpx / du, uy = gpy / du, uz = gpz / du;
    float nv = sqrtf(gqx * gqx + gqy * gqy + gqz * gqz);
    float dv = fmaxf(nv, EPSF);
    float vx = gqx / dv, vy = gqy / dv, vz = gqz / dv;

    float ax = uy * vz - uz * vy;
    float ay = uz * vx - ux * vz;
    float az = ux * vy - uy * vx;
    float an = sqrtf(ax * ax + ay * ay + az * az);
    float dot = ux * vx + uy * vy + uz * vz;
    dot = fminf(1.0f, fmaxf(-1.0f, dot));
    bool parallel = (an < 1e-6f);

    float kx = ax / (an + EPSF), ky = ay / (an + EPSF), kz = az / (an + EPSF);
    float theta = acosf(dot);
    float st = sinf(theta), ct = cosf(theta);

    float K[9] = {0.f, -kz, ky,  kz, 0.f, -kx,  -ky, kx, 0.f};
    float KK[9];
    for (int i = 0; i < 3; ++i)
        for (int j = 0; j < 3; ++j) {
            float s2 = 0.f;
            for (int l = 0; l < 3; ++l) s2 += K[i * 3 + l] * K[l * 3 + j];
            KK[i * 3 + j] = s2;
        }
    float R[9];
    for (int i = 0; i < 9; ++i) {
        float I = (i == 0 || i == 4 || i == 8) ? 1.f : 0.f;
        R[i] = I + st * K[i] + (1.f - ct) * KK[i];
    }
    if (parallel) {
        if (dot < 0.f) {
            float bx, by, bz;
            if (fabsf(ux) < 0.9f) { bx = 1.f; by = 0.f; bz = 0.f; }
            else                  { bx = 0.f; by = 1.f; bz = 0.f; }
            float cx = uy * bz - uz * by;
            float cy = uz * bx - ux * bz;
            float cz = ux * by - uy * bx;
            float cn = sqrtf(cx * cx + cy * cy + cz * cz);
            float cd = fmaxf(cn, EPSF);
            cx /= cd; cy /= cd; cz /= cd;
            float K2[9] = {0.f, -cz, cy,  cz, 0.f, -cx,  -cy, cx, 0.f};
            float K2K2[9];
            for (int i = 0; i < 3; ++i)
                for (int j = 0; j < 3; ++j) {
                    float s2 = 0.f;
                    for (int l = 0; l < 3; ++l) s2 += K2[i * 3 + l] * K2[l * 3 + j];
                    K2K2[i * 3 + j] = s2;
                }
            for (int i = 0; i < 9; ++i) {
                float I = (i == 0 || i == 4 || i == 8) ? 1.f : 0.f;
                R[i] = I + 2.f * K2K2[i];
            }
        } else if (dot > 0.f) {
            for (int i = 0; i < 9; ++i) R[i] = (i == 0 || i == 4 || i == 8) ? 1.f : 0.f;
        }
    }
    float ms0 = sums[0] / (float)NPTS, ms1 = sums[1] / (float)NPTS, ms2 = sums[2] / (float)NPTS;
    float mt0 = sums[3] / (float)NPTS, mt1 = sums[4] / (float)NPTS, mt2 = sums[5] / (float)NPTS;
    for (int i = 0; i < 9; ++i) R_out[i] = R[i];
    t_out[0] = mt0 - (R[0] * ms0 + R[1] * ms1 + R[2] * ms2);
    t_out[1] = mt1 - (R[3] * ms0 + R[4] * ms1 + R[5] * ms2);
    t_out[2] = mt2 - (R[6] * ms0 + R[7] * ms1 + R[8] * ms2);
}

// ============================================================================
// K0a: per-batch means + R/t -> global Rt only (verbatim R5-proven body).
// Grid NB x 256. No pack arrays (R10 proved stage-from-raw is bit-exact).
// ============================================================================
__global__ void k0a_rt(const float* __restrict__ src, const float* __restrict__ tgt,
                       const float* __restrict__ g_p, const float* __restrict__ g_q,
                       float* __restrict__ Rt) {
    const int b = blockIdx.x;
    const int tid = threadIdx.x;
    const float* S = src + (size_t)b * 3 * NPTS;
    const float* T = tgt + (size_t)b * 3 * NPTS;

    float acc[6] = {0.f, 0.f, 0.f, 0.f, 0.f, 0.f};
    for (int n = tid; n < NPTS; n += 256) {
        acc[0] += S[n]; acc[1] += S[NPTS + n]; acc[2] += S[2 * NPTS + n];
        acc[3] += T[n]; acc[4] += T[NPTS + n]; acc[5] += T[2 * NPTS + n];
    }
    __shared__ float red[256];
    __shared__ float sums[6];
    for (int c = 0; c < 6; ++c) {
        red[tid] = acc[c];
        __syncthreads();
        for (int s = 128; s > 0; s >>= 1) {
            if (tid < s) red[tid] += red[tid + s];
            __syncthreads();
        }
        if (tid == 0) sums[c] = red[0];
        __syncthreads();
    }
    if (tid == 0) {
        float Rg[9], tc[3];
        gravity_align_rt(g_p, g_q, sums, b, Rg, tc);
        for (int i = 0; i < 9; ++i) Rt[b * 16 + i] = Rg[i];
        Rt[b * 16 + 9]  = tc[0];
        Rt[b * 16 + 10] = tc[1];
        Rt[b * 16 + 11] = tc[2];
    }
}

// ============================================================================
// K1r: NN both directions, staging FROM RAW inputs + Rt (mega2 A-phase,
// bit-exact-proven R10). Grid (64, NB, 2) x 1024, 64KB LDS, 2 blocks/CU.
// Scan config verbatim R5/R9 (proven fastest): 16 stripes x 256 ascending,
// strict >, stripe-order combine -> first-occurrence argmin bit-exact.
// ============================================================================
__global__ void k1r(const float* __restrict__ src, const float* __restrict__ tgt,
                    const float* __restrict__ Rt,
                    float* __restrict__ nnp, int* __restrict__ idxp,
                    float* __restrict__ nnq, int* __restrict__ idxq) {
    const int b = blockIdx.y;
    const int z = blockIdx.z;
    const int tid = threadIdx.x;
    const float* S = src + (size_t)b * 3 * NPTS;
    const float* T = tgt + (size_t)b * 3 * NPTS;
    const float R0 = Rt[b*16+0], R1 = Rt[b*16+1], R2 = Rt[b*16+2];
    const float R3 = Rt[b*16+3], R4 = Rt[b*16+4], R5 = Rt[b*16+5];
    const float R6 = Rt[b*16+6], R7 = Rt[b*16+7], R8 = Rt[b*16+8];
    const float t0 = Rt[b*16+9], t1 = Rt[b*16+10], t2 = Rt[b*16+11];

    __shared__ float4 stage4[NPTS];  // 64 KB
    const int nl = tid & 63;
    const int stripe = tid >> 6;
    const int n = blockIdx.x * 64 + nl;
    float4 p;

    if (z == 0) {
        // stage = q-points from raw tgt (verbatim mega2-A)
        for (int i = tid; i < NPTS; i += 1024) {
            float q0 = T[i], q1 = T[NPTS + i], q2 = T[2 * NPTS + i];
            float w = (q0 * q0 + q1 * q1 + q2 * q2) * -0.5f;
            stage4[i] = make_float4(q0, q1, q2, w);
        }
        float s0 = S[n], s1 = S[NPTS + n], s2 = S[2 * NPTS + n];
        float p0 = R0 * s0 + R1 * s1 + R2 * s2 + t0;
        float p1 = R3 * s0 + R4 * s1 + R5 * s2 + t1;
        float p2 = R6 * s0 + R7 * s1 + R8 * s2 + t2;
        p = make_float4(p0, p1, p2, p0 * p0 + p1 * p1 + p2 * p2);
    } else {
        // stage = p-points (R-transformed src, verbatim mega2-A)
        for (int i = tid; i < NPTS; i += 1024) {
            float s0 = S[i], s1 = S[NPTS + i], s2 = S[2 * NPTS + i];
            float p0 = R0 * s0 + R1 * s1 + R2 * s2 + t0;
            float p1 = R3 * s0 + R4 * s1 + R5 * s2 + t1;
            float p2 = R6 * s0 + R7 * s1 + R8 * s2 + t2;
            float w = (p0 * p0 + p1 * p1 + p2 * p2) * -0.5f;
            stage4[i] = make_float4(p0, p1, p2, w);
        }
        float q0 = T[n], q1 = T[NPTS + n], q2 = T[2 * NPTS + n];
        p = make_float4(q0, q1, q2, q0 * q0 + q1 * q1 + q2 * q2);
    }
    __syncthreads();

    const int m0 = stripe << 8;
    float best = -3.4e38f;
    int bi = m0;
    #pragma unroll 8
    for (int m = m0; m < m0 + 256; ++m) {
        float4 q = stage4[m];
        float s = fmaf(p.x, q.x, fmaf(p.y, q.y, fmaf(p.z, q.z, q.w)));
        if (s > best) { best = s; bi = m; }
    }
    __syncthreads();

    float* combd = (float*)stage4;
    int* combi = (int*)(combd + 1024);
    combd[tid] = best;
    combi[tid] = bi;
    __syncthreads();
    if (stripe == 0) {
        for (int s2 = 1; s2 < 16; ++s2) {
            float d2 = combd[s2 * 64 + nl];
            int i2 = combi[s2 * 64 + nl];
            if (d2 > best) { best = d2; bi = i2; }  // ties: lower m wins
        }
        float d = fmaf(-2.0f, best, p.w);
        float* nn = z ? nnq : nnp;
        int* idx = z ? idxq : idxp;
        nn[b * NPTS + n] = sqrtf(fmaxf(d, 0.f) + EPSF);
        idx[b * NPTS + n] = bi;
    }
}

// ============================================================================
// KCr: median + weights, fully parallel. Grid (64, NB, 2) x 1024.
// Each block REDUNDANTLY computes its (b,z)'s lower median via the R9-proven
// 4-pass radix select (redundancy is free: 512 blocks run concurrently;
// R10 lesson: the 8-block version serialized the tail at 1.5% occupancy).
// Then threads 0..63 write weights for the block's own 64 points using the
// R10-proven recompute-from-raw arithmetic (verbatim mega2-B).
// ============================================================================
__global__ void kcr(const float* __restrict__ nnp, const float* __restrict__ nnq,
                    const int* __restrict__ idxp, const int* __restrict__ idxq,
                    const float* __restrict__ src_n, const float* __restrict__ tgt_n,
                    const float* __restrict__ Rt,
                    const float* __restrict__ g_q, const float* __restrict__ k_p,
                    const float* __restrict__ k_q, float* __restrict__ out) {
    const int x = blockIdx.x;
    const int b = blockIdx.y;
    const int z = blockIdx.z;
    const int tid = threadIdx.x;
    const int wid = tid >> 6;
    const int lane = tid & 63;
    const float* a = (z ? nnq : nnp) + b * NPTS;

    // ---- R9-proven radix select (verbatim) ----
    unsigned int v[4];
    #pragma unroll
    for (int j = 0; j < 4; ++j)
        v[j] = __float_as_uint(a[tid + j * 1024]);  // positive: uint order == float order

    __shared__ int hist[16][256];
    __shared__ int tot[256];
    __shared__ int digit_s, base_s;

    const int shifts[4]   = {23, 15, 7, 0};
    const unsigned him[4] = {0x00000000u, 0x7F800000u, 0x7FFF8000u, 0x7FFFFF80u};
    const unsigned dm[4]  = {0xFFu, 0xFFu, 0xFFu, 0x7Fu};

    unsigned int prefix = 0u;
    int rank = 2047;

    for (int p = 0; p < 4; ++p) {
        const int sh = shifts[p];
        const unsigned himask = him[p];
        const unsigned dmask = dm[p];

        for (int k2 = lane; k2 < 256; k2 += 64) hist[wid][k2] = 0;
        __syncthreads();

        #pragma unroll
        for (int j = 0; j < 4; ++j) {
            if ((v[j] & himask) == prefix)
                atomicAdd(&hist[wid][(v[j] >> sh) & dmask], 1);
        }
        __syncthreads();

        if (tid < 256) {
            int t = 0;
            #pragma unroll
            for (int w = 0; w < 16; ++w) t += hist[w][tid];
            tot[tid] = t;
        }
        __syncthreads();

        if (wid == 0) {
            int c0 = tot[4 * lane + 0], c1 = tot[4 * lane + 1];
            int c2 = tot[4 * lane + 2], c3 = tot[4 * lane + 3];
            int s = c0 + c1 + c2 + c3;
            int incl = s;
            #pragma unroll
            for (int o = 1; o < 64; o <<= 1) {
                int t = __shfl_up(incl, o, 64);
                if (lane >= o) incl += t;
            }
            int base = incl - s;
            int cs[4] = {c0, c1, c2, c3};
            #pragma unroll
            for (int k2 = 0; k2 < 4; ++k2) {
                if (cs[k2] > 0 && rank >= base && rank < base + cs[k2]) {
                    digit_s = 4 * lane + k2;   // unique writer
                    base_s = base;
                }
                base += cs[k2];
            }
        }
        __syncthreads();
        prefix |= ((unsigned)digit_s) << sh;
        rank -= base_s;
        __syncthreads();
    }
    const float tauv = 3.0f * __uint_as_float(prefix);

    // ---- weights for this block's 64 own points (verbatim mega2-B) ----
    if (tid < 64) {
        const int n = x * 64 + tid;
        const float* SN = src_n + (size_t)b * 3 * NPTS;
        const float* TN = tgt_n + (size_t)b * 3 * NPTS;
        const float R0 = Rt[b*16+0], R1 = Rt[b*16+1], R2 = Rt[b*16+2];
        const float R3 = Rt[b*16+3], R4 = Rt[b*16+4], R5 = Rt[b*16+5];
        const float R6 = Rt[b*16+6], R7 = Rt[b*16+7], R8 = Rt[b*16+8];
        const float gx = g_q[3 * b + 0], gy = g_q[3 * b + 1], gz = g_q[3 * b + 2];
        const float kp = k_p[b], kq = k_q[b];
        const float keff = kp * kq / (kp + kq + EPSF);

        float w;
        if (z == 0) {
            float a0 = SN[n], a1 = SN[NPTS + n], a2 = SN[2 * NPTS + n];
            float snx = R0 * a0 + R1 * a1 + R2 * a2;
            float sny = R3 * a0 + R4 * a1 + R5 * a2;
            float snz = R6 * a0 + R7 * a1 + R8 * a2;
            float inc = snx * gx + sny * gy + snz * gz;
            int jj = idxp[b * NPTS + n];
            float tnx = TN[jj], tny = TN[NPTS + jj], tnz = TN[2 * NPTS + jj];
            float incr = tnx * gx + tny * gy + tnz * gz;
            float diff = inc - incr;
            float arg = 9.0f - keff * diff * diff;
            float sig = 1.f / (1.f + expf(-arg));
            float geom = (a[n] <= tauv) ? 1.f : 0.f;
            w = sig * geom;
        } else {
            float tnx = TN[n], tny = TN[NPTS + n], tnz = TN[2 * NPTS + n];
            float inc = tnx * gx + tny * gy + tnz * gz;
            int jj = idxq[b * NPTS + n];
            float a0 = SN[jj], a1 = SN[NPTS + jj], a2 = SN[2 * NPTS + jj];
            float snx = R0 * a0 + R1 * a1 + R2 * a2;
            float sny = R3 * a0 + R4 * a1 + R5 * a2;
            float snz = R6 * a0 + R7 * a1 + R8 * a2;
            float incr = snx * gx + sny * gy + snz * gz;
            float diff = inc - incr;
            float arg = 9.0f - keff * diff * diff;
            float sig = 1.f / (1.f + expf(-arg));
            float geom = (a[n] <= tauv) ? 1.f : 0.f;
            w = sig * geom;
        }
        out[z * (NB * NPTS) + b * NPTS + n] = w;
    }
}

extern "C" void kernel_launch(void* const* d_in, const int* in_sizes, int n_in,
                              void* d_out, int out_size, void* d_ws, size_t ws_size,
                              hipStream_t stream) {
    const float* src   = (const float*)d_in[0];
    const float* tgt   = (const float*)d_in[1];
    const float* src_n = (const float*)d_in[2];
    const float* tgt_n = (const float*)d_in[3];
    const float* g_p   = (const float*)d_in[4];
    const float* k_p   = (const float*)d_in[5];
    const float* g_q   = (const float*)d_in[6];
    const float* k_q   = (const float*)d_in[7];
    float* out = (float*)d_out;

    const int BN = NB * NPTS;
    float* nnp = (float*)d_ws;
    float* nnq = nnp + BN;
    int* idxp = (int*)(nnq + BN);
    int* idxq = idxp + BN;
    float* Rt  = (float*)(idxq + BN);   // NB*16 floats

    k0a_rt<<<dim3(NB), dim3(256), 0, stream>>>(src, tgt, g_p, g_q, Rt);
    k1r<<<dim3(NPTS / 64, NB, 2), dim3(1024), 0, stream>>>(src, tgt, Rt,
                                                           nnp, idxp, nnq, idxq);
    kcr<<<dim3(NPTS / 64, NB, 2), dim3(1024), 0, stream>>>(nnp, nnq, idxp, idxq,
                                                           src_n, tgt_n, Rt,
                                                           g_q, k_p, k_q, out);
}